// Round 11
// baseline (207.932 us; speedup 1.0000x reference)
//
#include <hip/hip_runtime.h>

typedef __bf16 bf16x8 __attribute__((ext_vector_type(8)));
typedef float f32x4 __attribute__((ext_vector_type(4)));

// Native gfx950 bf16 convert (v_cvt_pk_bf16_f32), RNE — 1 VALU op vs 3-4
// for the manual bit-twiddle.
__device__ inline unsigned short f2bf(float f) {
    __bf16 b = (__bf16)f;
    return __builtin_bit_cast(unsigned short, b);
}

// async global->LDS, 16B per lane; LDS dest = wave-uniform base + lane*16
__device__ __forceinline__ void gl_lds16(const unsigned short* g, unsigned short* l)
{
    __builtin_amdgcn_global_load_lds(
        (const __attribute__((address_space(1))) void*)g,
        (__attribute__((address_space(3))) void*)l, 16, 0, 0);
}

// ---------------------------------------------------------------------------
// Fused prep: blocks [0,2048): x fp32 -> xb bf16 (8 elems/thread).
// Blocks [2048,2816): Wq/Wk/Wv fp32 [k][n] -> wqkvT bf16 [n][k] (64x64 tiles).
// ---------------------------------------------------------------------------
__global__ __launch_bounds__(256)
void prep(const float* __restrict__ x, unsigned short* __restrict__ xb,
          const float* __restrict__ Wq, const float* __restrict__ Wk,
          const float* __restrict__ Wv, unsigned short* __restrict__ wT)
{
    __shared__ unsigned short T[64][72];
    if (blockIdx.x < 2048) {
        const size_t i = ((size_t)blockIdx.x * 256 + threadIdx.x) * 8;
        float4 a = *reinterpret_cast<const float4*>(x + i);
        float4 b = *reinterpret_cast<const float4*>(x + i + 4);
        unsigned short t[8] = { f2bf(a.x), f2bf(a.y), f2bf(a.z), f2bf(a.w),
                                f2bf(b.x), f2bf(b.y), f2bf(b.z), f2bf(b.w) };
        *reinterpret_cast<uint4*>(xb + i) = *reinterpret_cast<uint4*>(t);
        return;
    }
    const int blk = blockIdx.x - 2048;
    const int z = blk >> 8, within = blk & 255;
    const float* W = (z == 0) ? Wq : (z == 1) ? Wk : Wv;
    unsigned short* dstBase = wT + (size_t)z * 1024 * 1024;
    const int k0 = (within >> 4) * 64, n0 = (within & 15) * 64;
    const int r = threadIdx.x >> 2, c0 = (threadIdx.x & 3) * 16;
    const float* src = W + (size_t)(k0 + r) * 1024 + n0 + c0;
    #pragma unroll
    for (int j = 0; j < 16; j += 4) {
        float4 f = *reinterpret_cast<const float4*>(src + j);
        T[r][c0 + j]     = f2bf(f.x);
        T[r][c0 + j + 1] = f2bf(f.y);
        T[r][c0 + j + 2] = f2bf(f.z);
        T[r][c0 + j + 3] = f2bf(f.w);
    }
    __syncthreads();
    unsigned short* dst = dstBase + (size_t)(n0 + r) * 1024 + k0 + c0;
    #pragma unroll
    for (int h = 0; h < 2; ++h) {
        unsigned short t8[8];
        #pragma unroll
        for (int j = 0; j < 8; ++j) t8[j] = T[c0 + h * 8 + j][r];
        *reinterpret_cast<uint4*>(dst + h * 8) = *reinterpret_cast<uint4*>(t8);
    }
}

// ---------------------------------------------------------------------------
// Transpose-convert (Wo): fp32 [k][n] -> bf16 [n][k].
// ---------------------------------------------------------------------------
__global__ __launch_bounds__(256)
void wconv(const float* __restrict__ W, unsigned short* __restrict__ wT)
{
    __shared__ unsigned short T[64][72];
    const int k0 = blockIdx.y * 64, n0 = blockIdx.x * 64;
    const int r = threadIdx.x >> 2, c0 = (threadIdx.x & 3) * 16;
    const float* src = W + (size_t)(k0 + r) * 1024 + n0 + c0;
    #pragma unroll
    for (int j = 0; j < 16; j += 4) {
        float4 f = *reinterpret_cast<const float4*>(src + j);
        T[r][c0 + j]     = f2bf(f.x);
        T[r][c0 + j + 1] = f2bf(f.y);
        T[r][c0 + j + 2] = f2bf(f.z);
        T[r][c0 + j + 3] = f2bf(f.w);
    }
    __syncthreads();
    unsigned short* dst = wT + (size_t)(n0 + r) * 1024 + k0 + c0;
    #pragma unroll
    for (int h = 0; h < 2; ++h) {
        unsigned short t8[8];
        #pragma unroll
        for (int j = 0; j < 8; ++j) t8[j] = T[c0 + h * 8 + j][r];
        *reinterpret_cast<uint4*>(dst + h * 8) = *reinterpret_cast<uint4*>(t8);
    }
}

// ---------------------------------------------------------------------------
// m97-style GEMM, BK=64 as TWO 32-k sub-tiles (halves barrier-drain count
// vs BK=32 while keeping the proven 128x32 LDS shape -> frag reads stay
// 2-way bank-aliased i.e. free; a single 128x64 tile would be 16-way).
// 128x128 tile, gl_lds width-16 staging, 4 waves 2x2, 4x4 mfma 16x16x32.
// MODE 0: QKV routing (q/k normal, v transposed). MODE 2: fp32 out + bias.
// ---------------------------------------------------------------------------
template <int MODE>
__global__ __launch_bounds__(256)
void gemm128(const unsigned short* __restrict__ A,
             const unsigned short* __restrict__ BT,
             void* __restrict__ C0, void* __restrict__ C1,
             void* __restrict__ C2, const float* __restrict__ bias)
{
    __shared__ unsigned short As[2][128 * 32];
    __shared__ unsigned short Bs[2][128 * 32];

    const int tid = threadIdx.x;
    const int wave = tid >> 6, lane = tid & 63, quad = lane >> 4, l16 = lane & 15;
    const int wm = wave >> 1, wn = wave & 1;
    const int mBase = blockIdx.y * 128, nBase = blockIdx.x * 128;

    f32x4 acc[4][4] = {};

    const int sa = lane >> 2, sb = (lane & 3) * 8;  // 16 rows x 32 shorts per op

    for (int kb = 0; kb < 1024; kb += 64) {
        __syncthreads();                 // prior frag reads done
        #pragma unroll
        for (int j = 0; j < 4; ++j) {
            const int op = wave * 4 + j;           // 0..15
            const int hh = op >> 3, rg = op & 7;   // k-half, 16-row group
            gl_lds16(A  + (size_t)(mBase + rg * 16 + sa) * 1024 + kb + hh * 32 + sb,
                     &As[hh][rg * 512]);
            gl_lds16(BT + (size_t)(nBase + rg * 16 + sa) * 1024 + kb + hh * 32 + sb,
                     &Bs[hh][rg * 512]);
        }
        __syncthreads();                 // drains DMA -> both sub-tiles visible

        #pragma unroll
        for (int kk = 0; kk < 2; ++kk) {
            bf16x8 af[4], bf[4];
            #pragma unroll
            for (int t = 0; t < 4; ++t) {
                af[t] = *reinterpret_cast<const bf16x8*>(&As[kk][(wm * 64 + t * 16 + l16) * 32 + quad * 8]);
                bf[t] = *reinterpret_cast<const bf16x8*>(&Bs[kk][(wn * 64 + t * 16 + l16) * 32 + quad * 8]);
            }
            #pragma unroll
            for (int ti = 0; ti < 4; ++ti)
                #pragma unroll
                for (int tj = 0; tj < 4; ++tj)
                    acc[ti][tj] = __builtin_amdgcn_mfma_f32_16x16x32_bf16(
                        af[ti], bf[tj], acc[ti][tj], 0, 0, 0);
        }
    }

    #pragma unroll
    for (int ti = 0; ti < 4; ++ti) {
        const int row0 = mBase + wm * 64 + ti * 16 + quad * 4;
        #pragma unroll
        for (int tj = 0; tj < 4; ++tj) {
            const int col = nBase + wn * 64 + tj * 16 + l16;
            if constexpr (MODE == 0) {
                if (col < 1024) {
                    unsigned short* qb = (unsigned short*)C0;
                    #pragma unroll
                    for (int i = 0; i < 4; ++i)
                        qb[(size_t)(row0 + i) * 1024 + col] = f2bf(acc[ti][tj][i]);
                } else if (col < 2048) {
                    unsigned short* kb = (unsigned short*)C1;
                    #pragma unroll
                    for (int i = 0; i < 4; ++i)
                        kb[(size_t)(row0 + i) * 1024 + col - 1024] = f2bf(acc[ti][tj][i]);
                } else {
                    unsigned short* vT = (unsigned short*)C2;
                    unsigned short t4[4] = { f2bf(acc[ti][tj][0]), f2bf(acc[ti][tj][1]),
                                             f2bf(acc[ti][tj][2]), f2bf(acc[ti][tj][3]) };
                    *reinterpret_cast<uint2*>(&vT[(size_t)(col - 2048) * 4096 + row0]) =
                        *reinterpret_cast<uint2*>(t4);
                }
            } else {
                float* out = (float*)C0;
                const float ba = bias[col];
                #pragma unroll
                for (int i = 0; i < 4; ++i)
                    out[(size_t)(row0 + i) * 1024 + col] = acc[ti][tj][i] + ba;
            }
        }
    }
}

// ---------------------------------------------------------------------------
// MFMA causal flash attention v6 (balanced triangle folding; R10: 54 us),
// plus: native bf16 cvt (v_cvt_pk_bf16_f32) and exp2-folded softmax
// (p = exp2(s * 0.125*log2e), one v_mul + v_exp).
// ---------------------------------------------------------------------------
#define LDP 72    // Ps row stride (shorts), 16B-aligned rows
#define EXP2_SCL 0.18033688011112042f   // 0.125 * log2(e)

__global__ __launch_bounds__(256)
void attn6(const unsigned short* __restrict__ q,
           const unsigned short* __restrict__ k,
           const unsigned short* __restrict__ vT,
           unsigned short* __restrict__ ctx)
{
    __shared__ unsigned short Ks[2][2][64 * 32]; // [buf][d-half][key][d%32]
    __shared__ unsigned short Vs[2][2][64 * 32]; // [buf][key-half][d][key%32]
    __shared__ unsigned short PsA[64 * LDP];
    __shared__ unsigned short PsB[64 * LDP];

    const int tid  = threadIdx.x;
    const int wave = tid >> 6, lane = tid & 63, quad = lane >> 4, l16 = lane & 15;
    const int j  = blockIdx.x;               // 0..15 pair index
    const int bh = blockIdx.y;
    const int b = bh >> 4, h = bh & 15;
    const int tokBase = b * 2048;
    const int colBase = h * 64;
    const int qtA = 31 - j, qtB = j;
    const int qBaseA = qtA * 64, qBaseB = qtB * 64;

    bf16x8 aqA[2], aqB[2];
    {
        const unsigned short* qrA =
            q + (size_t)(tokBase + qBaseA + wave * 16 + l16) * 1024 + colBase;
        aqA[0] = *reinterpret_cast<const bf16x8*>(qrA + quad * 8);
        aqA[1] = *reinterpret_cast<const bf16x8*>(qrA + 32 + quad * 8);
        const unsigned short* qrB =
            q + (size_t)(tokBase + qBaseB + wave * 16 + l16) * 1024 + colBase;
        aqB[0] = *reinterpret_cast<const bf16x8*>(qrB + quad * 8);
        aqB[1] = *reinterpret_cast<const bf16x8*>(qrB + 32 + quad * 8);
    }

    f32x4 oA[4] = {}, oB[4] = {};
    float lsA[4] = {}, lsB[4] = {};

    const int sa = lane >> 2;            // staging row-within-16
    const int sb = (lane & 3) * 8;       // staging 8-short col offset

    auto stage = [&](int tok0, int buf) {
        #pragma unroll
        for (int o = 0; o < 2; ++o) {
            const int op = wave * 2 + o;
            const int hh = op >> 2, rg = op & 3;
            gl_lds16(k + (size_t)(tok0 + rg * 16 + sa) * 1024 + colBase + hh * 32 + sb,
                     &Ks[buf][hh][rg * 16 * 32]);
            gl_lds16(vT + (size_t)(colBase + rg * 16 + sa) * 4096 + tok0 + hh * 32 + sb,
                     &Vs[buf][hh][rg * 16 * 32]);
        }
    };

    stage(tokBase, 0);
    __syncthreads();                     // drains tile-0 DMA

    const int nkt = qtA + 1;             // 64-key tiles (tile A's range)
    for (int kt = 0; kt < nkt; ++kt) {
        const int buf = kt & 1;
        if (kt + 1 < nkt)
            stage(tokBase + (kt + 1) * 64, buf ^ 1);   // async, lands by barrier

        const bool doB = (kt <= qtB);
        const bool diagA = (kt == qtA), diagB = (kt == qtB);

        // ---- QK^T + softmax, tile A
        {
            f32x4 sc[4] = {};
            #pragma unroll
            for (int t = 0; t < 4; ++t)
                #pragma unroll
                for (int kf = 0; kf < 2; ++kf) {
                    bf16x8 bk = *reinterpret_cast<const bf16x8*>(
                        &Ks[buf][kf][(t * 16 + l16) * 32 + quad * 8]);
                    sc[t] = __builtin_amdgcn_mfma_f32_16x16x32_bf16(aqA[kf], bk, sc[t], 0, 0, 0);
                }
            #pragma unroll
            for (int t = 0; t < 4; ++t) {
                const int ki = kt * 64 + t * 16 + l16;
                #pragma unroll
                for (int r = 0; r < 4; ++r) {
                    float p = exp2f(sc[t][r] * EXP2_SCL);
                    if (diagA && ki > qBaseA + wave * 16 + quad * 4 + r) p = 0.0f;
                    lsA[r] += p;
                    PsA[(wave * 16 + quad * 4 + r) * LDP + t * 16 + l16] = f2bf(p);
                }
            }
        }
        // ---- QK^T + softmax, tile B (shared k-tile)
        if (doB) {
            f32x4 sc[4] = {};
            #pragma unroll
            for (int t = 0; t < 4; ++t)
                #pragma unroll
                for (int kf = 0; kf < 2; ++kf) {
                    bf16x8 bk = *reinterpret_cast<const bf16x8*>(
                        &Ks[buf][kf][(t * 16 + l16) * 32 + quad * 8]);
                    sc[t] = __builtin_amdgcn_mfma_f32_16x16x32_bf16(aqB[kf], bk, sc[t], 0, 0, 0);
                }
            #pragma unroll
            for (int t = 0; t < 4; ++t) {
                const int ki = kt * 64 + t * 16 + l16;
                #pragma unroll
                for (int r = 0; r < 4; ++r) {
                    float p = exp2f(sc[t][r] * EXP2_SCL);
                    if (diagB && ki > qBaseB + wave * 16 + quad * 4 + r) p = 0.0f;
                    lsB[r] += p;
                    PsB[(wave * 16 + quad * 4 + r) * LDP + t * 16 + l16] = f2bf(p);
                }
            }
        }

        // ---- O += P @ V (wave-uniform skip of fully-masked frags on diag)
        #pragma unroll
        for (int kf = 0; kf < 2; ++kf) {
            if (diagA && (wave * 16 + 15) < kf * 32) continue;
            bf16x8 ap = *reinterpret_cast<const bf16x8*>(
                &PsA[(wave * 16 + l16) * LDP + kf * 32 + quad * 8]);
            #pragma unroll
            for (int t = 0; t < 4; ++t) {
                bf16x8 bv = *reinterpret_cast<const bf16x8*>(
                    &Vs[buf][kf][(t * 16 + l16) * 32 + quad * 8]);
                oA[t] = __builtin_amdgcn_mfma_f32_16x16x32_bf16(ap, bv, oA[t], 0, 0, 0);
            }
        }
        if (doB) {
            #pragma unroll
            for (int kf = 0; kf < 2; ++kf) {
                if (diagB && (wave * 16 + 15) < kf * 32) continue;
                bf16x8 ap = *reinterpret_cast<const bf16x8*>(
                    &PsB[(wave * 16 + l16) * LDP + kf * 32 + quad * 8]);
                #pragma unroll
                for (int t = 0; t < 4; ++t) {
                    bf16x8 bv = *reinterpret_cast<const bf16x8*>(
                        &Vs[buf][kf][(t * 16 + l16) * 32 + quad * 8]);
                    oB[t] = __builtin_amdgcn_mfma_f32_16x16x32_bf16(ap, bv, oB[t], 0, 0, 0);
                }
            }
        }

        if (kt + 1 < nkt)
            __syncthreads();             // drains prefetch; guards buffer swap
    }

    #pragma unroll
    for (int off = 1; off < 16; off <<= 1)
        #pragma unroll
        for (int r = 0; r < 4; ++r) {
            lsA[r] += __shfl_xor(lsA[r], off);
            lsB[r] += __shfl_xor(lsB[r], off);
        }

    #pragma unroll
    for (int r = 0; r < 4; ++r) {
        const float invA = 1.0f / lsA[r];
        const float invB = 1.0f / lsB[r];
        const size_t grA = (size_t)(tokBase + qBaseA + wave * 16 + quad * 4 + r) * 1024 + colBase;
        const size_t grB = (size_t)(tokBase + qBaseB + wave * 16 + quad * 4 + r) * 1024 + colBase;
        #pragma unroll
        for (int t = 0; t < 4; ++t) {
            ctx[grA + t * 16 + l16] = f2bf(oA[t][r] * invA);
            ctx[grB + t * 16 + l16] = f2bf(oB[t][r] * invB);
        }
    }
}

// ---------------------------------------------------------------------------
extern "C" void kernel_launch(void* const* d_in, const int* in_sizes, int n_in,
                              void* d_out, int out_size, void* d_ws, size_t ws_size,
                              hipStream_t stream)
{
    const float* x  = (const float*)d_in[0];   // [4096,1024] fp32
    const float* Wq = (const float*)d_in[1];
    const float* Wk = (const float*)d_in[2];
    const float* Wv = (const float*)d_in[3];
    const float* Wo = (const float*)d_in[4];
    const float* bo = (const float*)d_in[5];
    float* out = (float*)d_out;

    // ws (32 MB): xb -> ctx after gemm_qkv; kb -> woT after attn6.
    // d_out doubles as wqkvT scratch until gemm_out overwrites it.
    unsigned short* xb     = (unsigned short*)d_ws;           // 8 MB -> ctx
    unsigned short* qb     = xb + (size_t)4096 * 1024;        // 8 MB
    unsigned short* kb     = qb + (size_t)4096 * 1024;        // 8 MB -> woT
    unsigned short* vT     = kb + (size_t)4096 * 1024;        // 8 MB [1024][4096]
    unsigned short* ctx    = xb;
    unsigned short* wqkvT  = (unsigned short*)d_out;          // 6.3 MB scratch
    unsigned short* woT    = kb;

    prep<<<2816, 256, 0, stream>>>(x, xb, Wq, Wk, Wv, wqkvT);

    gemm128<0><<<dim3(24, 32), 256, 0, stream>>>(xb, wqkvT, qb, kb, vT, nullptr);

    attn6<<<dim3(16, 32), 256, 0, stream>>>(qb, kb, vT, ctx);

    wconv<<<dim3(16, 16), 256, 0, stream>>>(Wo, woT);

    gemm128<2><<<dim3(8, 32), 256, 0, stream>>>(ctx, woT, out, nullptr, nullptr, bo);
}

// Round 12
// 201.413 us; speedup vs baseline: 1.0324x; 1.0324x over previous
//
#include <hip/hip_runtime.h>

typedef __bf16 bf16x8 __attribute__((ext_vector_type(8)));
typedef float f32x4 __attribute__((ext_vector_type(4)));

// Manual RNE f2bf (finite inputs): 3 VALU ops. NOTE: (__bf16) cast lowers
// to a NaN-safe 4-5 op sequence (R11 regression) — keep the manual path.
__device__ inline unsigned short f2bf(float f) {
    unsigned int x = __builtin_bit_cast(unsigned int, f);
    x += 0x7fff + ((x >> 16) & 1);
    return (unsigned short)(x >> 16);
}

// async global->LDS, 16B per lane; LDS dest = wave-uniform base + lane*16
__device__ __forceinline__ void gl_lds16(const unsigned short* g, unsigned short* l)
{
    __builtin_amdgcn_global_load_lds(
        (const __attribute__((address_space(1))) void*)g,
        (__attribute__((address_space(3))) void*)l, 16, 0, 0);
}

// ---------------------------------------------------------------------------
// Fused prep: blocks [0,2048): x fp32 -> xb bf16 (8 elems/thread).
// Blocks [2048,2816): Wq/Wk/Wv fp32 [k][n] -> wqkvT bf16 [n][k] (64x64 tiles).
// ---------------------------------------------------------------------------
__global__ __launch_bounds__(256)
void prep(const float* __restrict__ x, unsigned short* __restrict__ xb,
          const float* __restrict__ Wq, const float* __restrict__ Wk,
          const float* __restrict__ Wv, unsigned short* __restrict__ wT)
{
    __shared__ unsigned short T[64][72];
    if (blockIdx.x < 2048) {
        const size_t i = ((size_t)blockIdx.x * 256 + threadIdx.x) * 8;
        float4 a = *reinterpret_cast<const float4*>(x + i);
        float4 b = *reinterpret_cast<const float4*>(x + i + 4);
        unsigned short t[8] = { f2bf(a.x), f2bf(a.y), f2bf(a.z), f2bf(a.w),
                                f2bf(b.x), f2bf(b.y), f2bf(b.z), f2bf(b.w) };
        *reinterpret_cast<uint4*>(xb + i) = *reinterpret_cast<uint4*>(t);
        return;
    }
    const int blk = blockIdx.x - 2048;
    const int z = blk >> 8, within = blk & 255;
    const float* W = (z == 0) ? Wq : (z == 1) ? Wk : Wv;
    unsigned short* dstBase = wT + (size_t)z * 1024 * 1024;
    const int k0 = (within >> 4) * 64, n0 = (within & 15) * 64;
    const int r = threadIdx.x >> 2, c0 = (threadIdx.x & 3) * 16;
    const float* src = W + (size_t)(k0 + r) * 1024 + n0 + c0;
    #pragma unroll
    for (int j = 0; j < 16; j += 4) {
        float4 f = *reinterpret_cast<const float4*>(src + j);
        T[r][c0 + j]     = f2bf(f.x);
        T[r][c0 + j + 1] = f2bf(f.y);
        T[r][c0 + j + 2] = f2bf(f.z);
        T[r][c0 + j + 3] = f2bf(f.w);
    }
    __syncthreads();
    unsigned short* dst = dstBase + (size_t)(n0 + r) * 1024 + k0 + c0;
    #pragma unroll
    for (int h = 0; h < 2; ++h) {
        unsigned short t8[8];
        #pragma unroll
        for (int j = 0; j < 8; ++j) t8[j] = T[c0 + h * 8 + j][r];
        *reinterpret_cast<uint4*>(dst + h * 8) = *reinterpret_cast<uint4*>(t8);
    }
}

// ---------------------------------------------------------------------------
// Transpose-convert (Wo): fp32 [k][n] -> bf16 [n][k].
// ---------------------------------------------------------------------------
__global__ __launch_bounds__(256)
void wconv(const float* __restrict__ W, unsigned short* __restrict__ wT)
{
    __shared__ unsigned short T[64][72];
    const int k0 = blockIdx.y * 64, n0 = blockIdx.x * 64;
    const int r = threadIdx.x >> 2, c0 = (threadIdx.x & 3) * 16;
    const float* src = W + (size_t)(k0 + r) * 1024 + n0 + c0;
    #pragma unroll
    for (int j = 0; j < 16; j += 4) {
        float4 f = *reinterpret_cast<const float4*>(src + j);
        T[r][c0 + j]     = f2bf(f.x);
        T[r][c0 + j + 1] = f2bf(f.y);
        T[r][c0 + j + 2] = f2bf(f.z);
        T[r][c0 + j + 3] = f2bf(f.w);
    }
    __syncthreads();
    unsigned short* dst = wT + (size_t)(n0 + r) * 1024 + k0 + c0;
    #pragma unroll
    for (int h = 0; h < 2; ++h) {
        unsigned short t8[8];
        #pragma unroll
        for (int j = 0; j < 8; ++j) t8[j] = T[c0 + h * 8 + j][r];
        *reinterpret_cast<uint4*>(dst + h * 8) = *reinterpret_cast<uint4*>(t8);
    }
}

// ---------------------------------------------------------------------------
// m97-style GEMM (R10 config: BK=32 — the BK=64 variant regressed in R11).
// 128x128 tile, unpadded LDS, gl_lds width-16 staging, 4 waves 2x2, 4x4 mfma.
// MODE 0: QKV routing (q/k normal, v transposed). MODE 2: fp32 out + bias.
// ---------------------------------------------------------------------------
template <int MODE>
__global__ __launch_bounds__(256)
void gemm128(const unsigned short* __restrict__ A,
             const unsigned short* __restrict__ BT,
             void* __restrict__ C0, void* __restrict__ C1,
             void* __restrict__ C2, const float* __restrict__ bias)
{
    __shared__ unsigned short As[128 * 32];
    __shared__ unsigned short Bs[128 * 32];

    const int tid = threadIdx.x;
    const int wave = tid >> 6, lane = tid & 63, quad = lane >> 4, l16 = lane & 15;
    const int wm = wave >> 1, wn = wave & 1;
    const int mBase = blockIdx.y * 128, nBase = blockIdx.x * 128;

    f32x4 acc[4][4] = {};

    const int srow = lane >> 2, sko = (lane & 3) * 8;

    for (int kb = 0; kb < 1024; kb += 32) {
        __syncthreads();
        #pragma unroll
        for (int j = 0; j < 2; ++j) {
            const int seg = wave * 2 + j;
            gl_lds16(A  + (size_t)(mBase + seg * 16 + srow) * 1024 + kb + sko,
                     As + seg * 512);
            gl_lds16(BT + (size_t)(nBase + seg * 16 + srow) * 1024 + kb + sko,
                     Bs + seg * 512);
        }
        __syncthreads();

        bf16x8 af[4], bf[4];
        #pragma unroll
        for (int t = 0; t < 4; ++t) {
            af[t] = *reinterpret_cast<const bf16x8*>(&As[(wm * 64 + t * 16 + l16) * 32 + quad * 8]);
            bf[t] = *reinterpret_cast<const bf16x8*>(&Bs[(wn * 64 + t * 16 + l16) * 32 + quad * 8]);
        }
        #pragma unroll
        for (int ti = 0; ti < 4; ++ti)
            #pragma unroll
            for (int tj = 0; tj < 4; ++tj)
                acc[ti][tj] = __builtin_amdgcn_mfma_f32_16x16x32_bf16(
                    af[ti], bf[tj], acc[ti][tj], 0, 0, 0);
    }

    #pragma unroll
    for (int ti = 0; ti < 4; ++ti) {
        const int row0 = mBase + wm * 64 + ti * 16 + quad * 4;
        #pragma unroll
        for (int tj = 0; tj < 4; ++tj) {
            const int col = nBase + wn * 64 + tj * 16 + l16;
            if constexpr (MODE == 0) {
                if (col < 1024) {
                    unsigned short* qb = (unsigned short*)C0;
                    #pragma unroll
                    for (int i = 0; i < 4; ++i)
                        qb[(size_t)(row0 + i) * 1024 + col] = f2bf(acc[ti][tj][i]);
                } else if (col < 2048) {
                    unsigned short* kb = (unsigned short*)C1;
                    #pragma unroll
                    for (int i = 0; i < 4; ++i)
                        kb[(size_t)(row0 + i) * 1024 + col - 1024] = f2bf(acc[ti][tj][i]);
                } else {
                    unsigned short* vT = (unsigned short*)C2;
                    unsigned short t4[4] = { f2bf(acc[ti][tj][0]), f2bf(acc[ti][tj][1]),
                                             f2bf(acc[ti][tj][2]), f2bf(acc[ti][tj][3]) };
                    *reinterpret_cast<uint2*>(&vT[(size_t)(col - 2048) * 4096 + row0]) =
                        *reinterpret_cast<uint2*>(t4);
                }
            } else {
                float* out = (float*)C0;
                const float ba = bias[col];
                #pragma unroll
                for (int i = 0; i < 4; ++i)
                    out[(size_t)(row0 + i) * 1024 + col] = acc[ti][tj][i] + ba;
            }
        }
    }
}

// ---------------------------------------------------------------------------
// MFMA causal flash attention v6 (R10 numerics: manual f2bf, __expf) with
// XCD-CLUSTERED grid: 512 flat blocks; decode puts all 16 pair-blocks of a
// (b,h) on one XCD (heuristic xcd = blk & 7, round-robin dispatch), so the
// head's 0.5 MB K/V slice is fetched into that XCD's 4 MB L2 ONCE instead
// of 8x (R10/R11 FETCH_SIZE 66-70 MB vs ~25 MB ideal).
// Balanced triangle folding: block pair (31-j, j) -> equal work, no tail.
// ---------------------------------------------------------------------------
#define LDP 72    // Ps row stride (shorts), 16B-aligned rows

__global__ __launch_bounds__(256)
void attn6(const unsigned short* __restrict__ q,
           const unsigned short* __restrict__ k,
           const unsigned short* __restrict__ vT,
           unsigned short* __restrict__ ctx)
{
    __shared__ unsigned short Ks[2][2][64 * 32]; // [buf][d-half][key][d%32]
    __shared__ unsigned short Vs[2][2][64 * 32]; // [buf][key-half][d][key%32]
    __shared__ unsigned short PsA[64 * LDP];
    __shared__ unsigned short PsB[64 * LDP];

    const int tid  = threadIdx.x;
    const int wave = tid >> 6, lane = tid & 63, quad = lane >> 4, l16 = lane & 15;
    // XCD-clustered decode: blk & 7 = XCD (heuristic); 4 bh per XCD.
    const int blk  = blockIdx.x;
    const int xcd  = blk & 7, slot = blk >> 3;
    const int bh   = xcd * 4 + (slot >> 4);
    const int j    = slot & 15;              // 0..15 pair index
    const int b = bh >> 4, h = bh & 15;
    const int tokBase = b * 2048;
    const int colBase = h * 64;
    const int qtA = 31 - j, qtB = j;
    const int qBaseA = qtA * 64, qBaseB = qtB * 64;

    bf16x8 aqA[2], aqB[2];
    {
        const unsigned short* qrA =
            q + (size_t)(tokBase + qBaseA + wave * 16 + l16) * 1024 + colBase;
        aqA[0] = *reinterpret_cast<const bf16x8*>(qrA + quad * 8);
        aqA[1] = *reinterpret_cast<const bf16x8*>(qrA + 32 + quad * 8);
        const unsigned short* qrB =
            q + (size_t)(tokBase + qBaseB + wave * 16 + l16) * 1024 + colBase;
        aqB[0] = *reinterpret_cast<const bf16x8*>(qrB + quad * 8);
        aqB[1] = *reinterpret_cast<const bf16x8*>(qrB + 32 + quad * 8);
    }

    f32x4 oA[4] = {}, oB[4] = {};
    float lsA[4] = {}, lsB[4] = {};

    const int sa = lane >> 2;            // staging row-within-16
    const int sb = (lane & 3) * 8;       // staging 8-short col offset

    auto stage = [&](int tok0, int buf) {
        #pragma unroll
        for (int o = 0; o < 2; ++o) {
            const int op = wave * 2 + o;
            const int hh = op >> 2, rg = op & 3;
            gl_lds16(k + (size_t)(tok0 + rg * 16 + sa) * 1024 + colBase + hh * 32 + sb,
                     &Ks[buf][hh][rg * 16 * 32]);
            gl_lds16(vT + (size_t)(colBase + rg * 16 + sa) * 4096 + tok0 + hh * 32 + sb,
                     &Vs[buf][hh][rg * 16 * 32]);
        }
    };

    stage(tokBase, 0);
    __syncthreads();                     // drains tile-0 DMA

    const int nkt = qtA + 1;             // 64-key tiles (tile A's range)
    for (int kt = 0; kt < nkt; ++kt) {
        const int buf = kt & 1;
        if (kt + 1 < nkt)
            stage(tokBase + (kt + 1) * 64, buf ^ 1);   // async, lands by barrier

        const bool doB = (kt <= qtB);
        const bool diagA = (kt == qtA), diagB = (kt == qtB);

        // ---- QK^T + softmax, tile A
        {
            f32x4 sc[4] = {};
            #pragma unroll
            for (int t = 0; t < 4; ++t)
                #pragma unroll
                for (int kf = 0; kf < 2; ++kf) {
                    bf16x8 bk = *reinterpret_cast<const bf16x8*>(
                        &Ks[buf][kf][(t * 16 + l16) * 32 + quad * 8]);
                    sc[t] = __builtin_amdgcn_mfma_f32_16x16x32_bf16(aqA[kf], bk, sc[t], 0, 0, 0);
                }
            #pragma unroll
            for (int t = 0; t < 4; ++t) {
                const int ki = kt * 64 + t * 16 + l16;
                #pragma unroll
                for (int r = 0; r < 4; ++r) {
                    float p = __expf(sc[t][r] * 0.125f);
                    if (diagA && ki > qBaseA + wave * 16 + quad * 4 + r) p = 0.0f;
                    lsA[r] += p;
                    PsA[(wave * 16 + quad * 4 + r) * LDP + t * 16 + l16] = f2bf(p);
                }
            }
        }
        // ---- QK^T + softmax, tile B (shared k-tile)
        if (doB) {
            f32x4 sc[4] = {};
            #pragma unroll
            for (int t = 0; t < 4; ++t)
                #pragma unroll
                for (int kf = 0; kf < 2; ++kf) {
                    bf16x8 bk = *reinterpret_cast<const bf16x8*>(
                        &Ks[buf][kf][(t * 16 + l16) * 32 + quad * 8]);
                    sc[t] = __builtin_amdgcn_mfma_f32_16x16x32_bf16(aqB[kf], bk, sc[t], 0, 0, 0);
                }
            #pragma unroll
            for (int t = 0; t < 4; ++t) {
                const int ki = kt * 64 + t * 16 + l16;
                #pragma unroll
                for (int r = 0; r < 4; ++r) {
                    float p = __expf(sc[t][r] * 0.125f);
                    if (diagB && ki > qBaseB + wave * 16 + quad * 4 + r) p = 0.0f;
                    lsB[r] += p;
                    PsB[(wave * 16 + quad * 4 + r) * LDP + t * 16 + l16] = f2bf(p);
                }
            }
        }

        // ---- O += P @ V (wave-uniform skip of fully-masked frags on diag)
        #pragma unroll
        for (int kf = 0; kf < 2; ++kf) {
            if (diagA && (wave * 16 + 15) < kf * 32) continue;
            bf16x8 ap = *reinterpret_cast<const bf16x8*>(
                &PsA[(wave * 16 + l16) * LDP + kf * 32 + quad * 8]);
            #pragma unroll
            for (int t = 0; t < 4; ++t) {
                bf16x8 bv = *reinterpret_cast<const bf16x8*>(
                    &Vs[buf][kf][(t * 16 + l16) * 32 + quad * 8]);
                oA[t] = __builtin_amdgcn_mfma_f32_16x16x32_bf16(ap, bv, oA[t], 0, 0, 0);
            }
        }
        if (doB) {
            #pragma unroll
            for (int kf = 0; kf < 2; ++kf) {
                if (diagB && (wave * 16 + 15) < kf * 32) continue;
                bf16x8 ap = *reinterpret_cast<const bf16x8*>(
                    &PsB[(wave * 16 + l16) * LDP + kf * 32 + quad * 8]);
                #pragma unroll
                for (int t = 0; t < 4; ++t) {
                    bf16x8 bv = *reinterpret_cast<const bf16x8*>(
                        &Vs[buf][kf][(t * 16 + l16) * 32 + quad * 8]);
                    oB[t] = __builtin_amdgcn_mfma_f32_16x16x32_bf16(ap, bv, oB[t], 0, 0, 0);
                }
            }
        }

        if (kt + 1 < nkt)
            __syncthreads();             // drains prefetch; guards buffer swap
    }

    #pragma unroll
    for (int off = 1; off < 16; off <<= 1)
        #pragma unroll
        for (int r = 0; r < 4; ++r) {
            lsA[r] += __shfl_xor(lsA[r], off);
            lsB[r] += __shfl_xor(lsB[r], off);
        }

    #pragma unroll
    for (int r = 0; r < 4; ++r) {
        const float invA = 1.0f / lsA[r];
        const float invB = 1.0f / lsB[r];
        const size_t grA = (size_t)(tokBase + qBaseA + wave * 16 + quad * 4 + r) * 1024 + colBase;
        const size_t grB = (size_t)(tokBase + qBaseB + wave * 16 + quad * 4 + r) * 1024 + colBase;
        #pragma unroll
        for (int t = 0; t < 4; ++t) {
            ctx[grA + t * 16 + l16] = f2bf(oA[t][r] * invA);
            ctx[grB + t * 16 + l16] = f2bf(oB[t][r] * invB);
        }
    }
}

// ---------------------------------------------------------------------------
extern "C" void kernel_launch(void* const* d_in, const int* in_sizes, int n_in,
                              void* d_out, int out_size, void* d_ws, size_t ws_size,
                              hipStream_t stream)
{
    const float* x  = (const float*)d_in[0];   // [4096,1024] fp32
    const float* Wq = (const float*)d_in[1];
    const float* Wk = (const float*)d_in[2];
    const float* Wv = (const float*)d_in[3];
    const float* Wo = (const float*)d_in[4];
    const float* bo = (const float*)d_in[5];
    float* out = (float*)d_out;

    // ws (32 MB): xb -> ctx after gemm_qkv; kb -> woT after attn6.
    // d_out doubles as wqkvT scratch until gemm_out overwrites it.
    unsigned short* xb     = (unsigned short*)d_ws;           // 8 MB -> ctx
    unsigned short* qb     = xb + (size_t)4096 * 1024;        // 8 MB
    unsigned short* kb     = qb + (size_t)4096 * 1024;        // 8 MB -> woT
    unsigned short* vT     = kb + (size_t)4096 * 1024;        // 8 MB [1024][4096]
    unsigned short* ctx    = xb;
    unsigned short* wqkvT  = (unsigned short*)d_out;          // 6.3 MB scratch
    unsigned short* woT    = kb;

    prep<<<2816, 256, 0, stream>>>(x, xb, Wq, Wk, Wv, wqkvT);

    gemm128<0><<<dim3(24, 32), 256, 0, stream>>>(xb, wqkvT, qb, kb, vT, nullptr);

    attn6<<<512, 256, 0, stream>>>(qb, kb, vT, ctx);

    wconv<<<dim3(16, 16), 256, 0, stream>>>(Wo, woT);

    gemm128<2><<<dim3(8, 32), 256, 0, stream>>>(ctx, woT, out, nullptr, nullptr, bo);
}

// Round 13
// 194.732 us; speedup vs baseline: 1.0678x; 1.0343x over previous
//
#include <hip/hip_runtime.h>

typedef __bf16 bf16x8 __attribute__((ext_vector_type(8)));
typedef float f32x4 __attribute__((ext_vector_type(4)));

// Manual RNE f2bf (finite inputs): 3 VALU ops. NOTE: (__bf16) cast lowers
// to a NaN-safe 4-5 op sequence (R11 regression) — keep the manual path.
__device__ inline unsigned short f2bf(float f) {
    unsigned int x = __builtin_bit_cast(unsigned int, f);
    x += 0x7fff + ((x >> 16) & 1);
    return (unsigned short)(x >> 16);
}

// async global->LDS, 16B per lane; LDS dest = wave-uniform base + lane*16
__device__ __forceinline__ void gl_lds16(const unsigned short* g, unsigned short* l)
{
    __builtin_amdgcn_global_load_lds(
        (const __attribute__((address_space(1))) void*)g,
        (__attribute__((address_space(3))) void*)l, 16, 0, 0);
}

// ---------------------------------------------------------------------------
// Fused prep: blocks [0,2048): x fp32 -> xb bf16 (8 elems/thread).
// Blocks [2048,2816): Wq/Wk/Wv fp32 [k][n] -> wqkvT bf16 [n][k] (64x64 tiles).
// ---------------------------------------------------------------------------
__global__ __launch_bounds__(256)
void prep(const float* __restrict__ x, unsigned short* __restrict__ xb,
          const float* __restrict__ Wq, const float* __restrict__ Wk,
          const float* __restrict__ Wv, unsigned short* __restrict__ wT)
{
    __shared__ unsigned short T[64][72];
    if (blockIdx.x < 2048) {
        const size_t i = ((size_t)blockIdx.x * 256 + threadIdx.x) * 8;
        float4 a = *reinterpret_cast<const float4*>(x + i);
        float4 b = *reinterpret_cast<const float4*>(x + i + 4);
        unsigned short t[8] = { f2bf(a.x), f2bf(a.y), f2bf(a.z), f2bf(a.w),
                                f2bf(b.x), f2bf(b.y), f2bf(b.z), f2bf(b.w) };
        *reinterpret_cast<uint4*>(xb + i) = *reinterpret_cast<uint4*>(t);
        return;
    }
    const int blk = blockIdx.x - 2048;
    const int z = blk >> 8, within = blk & 255;
    const float* W = (z == 0) ? Wq : (z == 1) ? Wk : Wv;
    unsigned short* dstBase = wT + (size_t)z * 1024 * 1024;
    const int k0 = (within >> 4) * 64, n0 = (within & 15) * 64;
    const int r = threadIdx.x >> 2, c0 = (threadIdx.x & 3) * 16;
    const float* src = W + (size_t)(k0 + r) * 1024 + n0 + c0;
    #pragma unroll
    for (int j = 0; j < 16; j += 4) {
        float4 f = *reinterpret_cast<const float4*>(src + j);
        T[r][c0 + j]     = f2bf(f.x);
        T[r][c0 + j + 1] = f2bf(f.y);
        T[r][c0 + j + 2] = f2bf(f.z);
        T[r][c0 + j + 3] = f2bf(f.w);
    }
    __syncthreads();
    unsigned short* dst = dstBase + (size_t)(n0 + r) * 1024 + k0 + c0;
    #pragma unroll
    for (int h = 0; h < 2; ++h) {
        unsigned short t8[8];
        #pragma unroll
        for (int j = 0; j < 8; ++j) t8[j] = T[c0 + h * 8 + j][r];
        *reinterpret_cast<uint4*>(dst + h * 8) = *reinterpret_cast<uint4*>(t8);
    }
}

// ---------------------------------------------------------------------------
// Transpose-convert (Wo): fp32 [k][n] -> bf16 [n][k].
// ---------------------------------------------------------------------------
__global__ __launch_bounds__(256)
void wconv(const float* __restrict__ W, unsigned short* __restrict__ wT)
{
    __shared__ unsigned short T[64][72];
    const int k0 = blockIdx.y * 64, n0 = blockIdx.x * 64;
    const int r = threadIdx.x >> 2, c0 = (threadIdx.x & 3) * 16;
    const float* src = W + (size_t)(k0 + r) * 1024 + n0 + c0;
    #pragma unroll
    for (int j = 0; j < 16; j += 4) {
        float4 f = *reinterpret_cast<const float4*>(src + j);
        T[r][c0 + j]     = f2bf(f.x);
        T[r][c0 + j + 1] = f2bf(f.y);
        T[r][c0 + j + 2] = f2bf(f.z);
        T[r][c0 + j + 3] = f2bf(f.w);
    }
    __syncthreads();
    unsigned short* dst = wT + (size_t)(n0 + r) * 1024 + k0 + c0;
    #pragma unroll
    for (int h = 0; h < 2; ++h) {
        unsigned short t8[8];
        #pragma unroll
        for (int j = 0; j < 8; ++j) t8[j] = T[c0 + h * 8 + j][r];
        *reinterpret_cast<uint4*>(dst + h * 8) = *reinterpret_cast<uint4*>(t8);
    }
}

// ---------------------------------------------------------------------------
// m97-style QKV GEMM (R10 config, proven): 128x128 tile, BK=32, unpadded
// LDS, gl_lds width-16 staging, 4 waves 2x2, 4x4 mfma. 768 blocks = 3/CU.
// QKV routing: q/k normal, v transposed.
// ---------------------------------------------------------------------------
__global__ __launch_bounds__(256)
void gemm_qkv(const unsigned short* __restrict__ A,
              const unsigned short* __restrict__ BT,
              unsigned short* __restrict__ qb, unsigned short* __restrict__ kb,
              unsigned short* __restrict__ vT)
{
    __shared__ unsigned short As[128 * 32];
    __shared__ unsigned short Bs[128 * 32];

    const int tid = threadIdx.x;
    const int wave = tid >> 6, lane = tid & 63, quad = lane >> 4, l16 = lane & 15;
    const int wm = wave >> 1, wn = wave & 1;
    const int mBase = blockIdx.y * 128, nBase = blockIdx.x * 128;

    f32x4 acc[4][4] = {};

    const int srow = lane >> 2, sko = (lane & 3) * 8;

    for (int kb_ = 0; kb_ < 1024; kb_ += 32) {
        __syncthreads();
        #pragma unroll
        for (int j = 0; j < 2; ++j) {
            const int seg = wave * 2 + j;
            gl_lds16(A  + (size_t)(mBase + seg * 16 + srow) * 1024 + kb_ + sko,
                     As + seg * 512);
            gl_lds16(BT + (size_t)(nBase + seg * 16 + srow) * 1024 + kb_ + sko,
                     Bs + seg * 512);
        }
        __syncthreads();

        bf16x8 af[4], bf[4];
        #pragma unroll
        for (int t = 0; t < 4; ++t) {
            af[t] = *reinterpret_cast<const bf16x8*>(&As[(wm * 64 + t * 16 + l16) * 32 + quad * 8]);
            bf[t] = *reinterpret_cast<const bf16x8*>(&Bs[(wn * 64 + t * 16 + l16) * 32 + quad * 8]);
        }
        #pragma unroll
        for (int ti = 0; ti < 4; ++ti)
            #pragma unroll
            for (int tj = 0; tj < 4; ++tj)
                acc[ti][tj] = __builtin_amdgcn_mfma_f32_16x16x32_bf16(
                    af[ti], bf[tj], acc[ti][tj], 0, 0, 0);
    }

    #pragma unroll
    for (int ti = 0; ti < 4; ++ti) {
        const int row0 = mBase + wm * 64 + ti * 16 + quad * 4;
        #pragma unroll
        for (int tj = 0; tj < 4; ++tj) {
            const int col = nBase + wn * 64 + tj * 16 + l16;
            if (col < 1024) {
                #pragma unroll
                for (int i = 0; i < 4; ++i)
                    qb[(size_t)(row0 + i) * 1024 + col] = f2bf(acc[ti][tj][i]);
            } else if (col < 2048) {
                #pragma unroll
                for (int i = 0; i < 4; ++i)
                    kb[(size_t)(row0 + i) * 1024 + col - 1024] = f2bf(acc[ti][tj][i]);
            } else {
                unsigned short t4[4] = { f2bf(acc[ti][tj][0]), f2bf(acc[ti][tj][1]),
                                         f2bf(acc[ti][tj][2]), f2bf(acc[ti][tj][3]) };
                *reinterpret_cast<uint2*>(&vT[(size_t)(col - 2048) * 4096 + row0]) =
                    *reinterpret_cast<uint2*>(t4);
            }
        }
    }
}

// ---------------------------------------------------------------------------
// Output GEMM, 64x128 tiles -> grid (8,64) = 512 blocks = 2/CU. R12 analysis:
// the old 128x128 grid was 256 blocks = 1 block/CU — no co-resident waves to
// hide the barrier drain (same failure mode as attn4). Wave-tile 32x64,
// acc 2x4, BK=32, gl_lds staging (12 ops/iter: A=4, B=8; 3 per wave,
// wave-uniform split). fp32 out + bias.
// ---------------------------------------------------------------------------
__global__ __launch_bounds__(256)
void gemm_out64(const unsigned short* __restrict__ A,
                const unsigned short* __restrict__ BT,
                float* __restrict__ out, const float* __restrict__ bias)
{
    __shared__ unsigned short As[64 * 32];
    __shared__ unsigned short Bs[128 * 32];

    const int tid = threadIdx.x;
    const int wave = tid >> 6, lane = tid & 63, quad = lane >> 4, l16 = lane & 15;
    const int wm = wave >> 1, wn = wave & 1;
    const int mBase = blockIdx.y * 64, nBase = blockIdx.x * 128;

    f32x4 acc[2][4] = {};

    const int sa = lane >> 2, sb = (lane & 3) * 8;

    for (int kb = 0; kb < 1024; kb += 32) {
        __syncthreads();
        #pragma unroll
        for (int j = 0; j < 3; ++j) {
            const int op = wave * 3 + j;       // 0..11, wave-uniform
            if (op < 4) {
                gl_lds16(A + (size_t)(mBase + op * 16 + sa) * 1024 + kb + sb,
                         As + op * 512);
            } else {
                const int rg = op - 4;         // 0..7
                gl_lds16(BT + (size_t)(nBase + rg * 16 + sa) * 1024 + kb + sb,
                         Bs + rg * 512);
            }
        }
        __syncthreads();

        bf16x8 af[2], bf[4];
        #pragma unroll
        for (int t = 0; t < 2; ++t)
            af[t] = *reinterpret_cast<const bf16x8*>(&As[(wm * 32 + t * 16 + l16) * 32 + quad * 8]);
        #pragma unroll
        for (int t = 0; t < 4; ++t)
            bf[t] = *reinterpret_cast<const bf16x8*>(&Bs[(wn * 64 + t * 16 + l16) * 32 + quad * 8]);
        #pragma unroll
        for (int ti = 0; ti < 2; ++ti)
            #pragma unroll
            for (int tj = 0; tj < 4; ++tj)
                acc[ti][tj] = __builtin_amdgcn_mfma_f32_16x16x32_bf16(
                    af[ti], bf[tj], acc[ti][tj], 0, 0, 0);
    }

    #pragma unroll
    for (int ti = 0; ti < 2; ++ti) {
        const int row0 = mBase + wm * 32 + ti * 16 + quad * 4;
        #pragma unroll
        for (int tj = 0; tj < 4; ++tj) {
            const int col = nBase + wn * 64 + tj * 16 + l16;
            const float ba = bias[col];
            #pragma unroll
            for (int i = 0; i < 4; ++i)
                out[(size_t)(row0 + i) * 1024 + col] = acc[ti][tj][i] + ba;
        }
    }
}

// ---------------------------------------------------------------------------
// MFMA causal flash attention v6 — EXACT R10 form (54 us proven).
// Balanced triangle folding: block (j, bh) owns q-tile pair (31-j, j) ->
// equal work, no skew tail. gl_lds dbuf staging, 1 barrier/iter, no running
// max (scores bounded), masked P=0, per-lane l, butterfly at end.
// R12 lesson: XCD-clustered decode cut FETCH 66->12 MB but cost +6 us
// (kernel is not HBM-bound; codegen perturbation hurt) — keep R10 grid.
// ---------------------------------------------------------------------------
#define LDP 72    // Ps row stride (shorts), 16B-aligned rows

__global__ __launch_bounds__(256)
void attn6(const unsigned short* __restrict__ q,
           const unsigned short* __restrict__ k,
           const unsigned short* __restrict__ vT,
           unsigned short* __restrict__ ctx)
{
    __shared__ unsigned short Ks[2][2][64 * 32]; // [buf][d-half][key][d%32]
    __shared__ unsigned short Vs[2][2][64 * 32]; // [buf][key-half][d][key%32]
    __shared__ unsigned short PsA[64 * LDP];
    __shared__ unsigned short PsB[64 * LDP];

    const int tid  = threadIdx.x;
    const int wave = tid >> 6, lane = tid & 63, quad = lane >> 4, l16 = lane & 15;
    const int j  = blockIdx.x;               // 0..15 pair index
    const int bh = blockIdx.y;
    const int b = bh >> 4, h = bh & 15;
    const int tokBase = b * 2048;
    const int colBase = h * 64;
    const int qtA = 31 - j, qtB = j;
    const int qBaseA = qtA * 64, qBaseB = qtB * 64;

    bf16x8 aqA[2], aqB[2];
    {
        const unsigned short* qrA =
            q + (size_t)(tokBase + qBaseA + wave * 16 + l16) * 1024 + colBase;
        aqA[0] = *reinterpret_cast<const bf16x8*>(qrA + quad * 8);
        aqA[1] = *reinterpret_cast<const bf16x8*>(qrA + 32 + quad * 8);
        const unsigned short* qrB =
            q + (size_t)(tokBase + qBaseB + wave * 16 + l16) * 1024 + colBase;
        aqB[0] = *reinterpret_cast<const bf16x8*>(qrB + quad * 8);
        aqB[1] = *reinterpret_cast<const bf16x8*>(qrB + 32 + quad * 8);
    }

    f32x4 oA[4] = {}, oB[4] = {};
    float lsA[4] = {}, lsB[4] = {};

    const int sa = lane >> 2;            // staging row-within-16
    const int sb = (lane & 3) * 8;       // staging 8-short col offset

    auto stage = [&](int tok0, int buf) {
        #pragma unroll
        for (int o = 0; o < 2; ++o) {
            const int op = wave * 2 + o;
            const int hh = op >> 2, rg = op & 3;
            gl_lds16(k + (size_t)(tok0 + rg * 16 + sa) * 1024 + colBase + hh * 32 + sb,
                     &Ks[buf][hh][rg * 16 * 32]);
            gl_lds16(vT + (size_t)(colBase + rg * 16 + sa) * 4096 + tok0 + hh * 32 + sb,
                     &Vs[buf][hh][rg * 16 * 32]);
        }
    };

    stage(tokBase, 0);
    __syncthreads();                     // drains tile-0 DMA

    const int nkt = qtA + 1;             // 64-key tiles (tile A's range)
    for (int kt = 0; kt < nkt; ++kt) {
        const int buf = kt & 1;
        if (kt + 1 < nkt)
            stage(tokBase + (kt + 1) * 64, buf ^ 1);   // async, lands by barrier

        const bool doB = (kt <= qtB);
        const bool diagA = (kt == qtA), diagB = (kt == qtB);

        // ---- QK^T + softmax, tile A
        {
            f32x4 sc[4] = {};
            #pragma unroll
            for (int t = 0; t < 4; ++t)
                #pragma unroll
                for (int kf = 0; kf < 2; ++kf) {
                    bf16x8 bk = *reinterpret_cast<const bf16x8*>(
                        &Ks[buf][kf][(t * 16 + l16) * 32 + quad * 8]);
                    sc[t] = __builtin_amdgcn_mfma_f32_16x16x32_bf16(aqA[kf], bk, sc[t], 0, 0, 0);
                }
            #pragma unroll
            for (int t = 0; t < 4; ++t) {
                const int ki = kt * 64 + t * 16 + l16;
                #pragma unroll
                for (int r = 0; r < 4; ++r) {
                    float p = __expf(sc[t][r] * 0.125f);
                    if (diagA && ki > qBaseA + wave * 16 + quad * 4 + r) p = 0.0f;
                    lsA[r] += p;
                    PsA[(wave * 16 + quad * 4 + r) * LDP + t * 16 + l16] = f2bf(p);
                }
            }
        }
        // ---- QK^T + softmax, tile B (shared k-tile)
        if (doB) {
            f32x4 sc[4] = {};
            #pragma unroll
            for (int t = 0; t < 4; ++t)
                #pragma unroll
                for (int kf = 0; kf < 2; ++kf) {
                    bf16x8 bk = *reinterpret_cast<const bf16x8*>(
                        &Ks[buf][kf][(t * 16 + l16) * 32 + quad * 8]);
                    sc[t] = __builtin_amdgcn_mfma_f32_16x16x32_bf16(aqB[kf], bk, sc[t], 0, 0, 0);
                }
            #pragma unroll
            for (int t = 0; t < 4; ++t) {
                const int ki = kt * 64 + t * 16 + l16;
                #pragma unroll
                for (int r = 0; r < 4; ++r) {
                    float p = __expf(sc[t][r] * 0.125f);
                    if (diagB && ki > qBaseB + wave * 16 + quad * 4 + r) p = 0.0f;
                    lsB[r] += p;
                    PsB[(wave * 16 + quad * 4 + r) * LDP + t * 16 + l16] = f2bf(p);
                }
            }
        }

        // ---- O += P @ V (wave-uniform skip of fully-masked frags on diag)
        #pragma unroll
        for (int kf = 0; kf < 2; ++kf) {
            if (diagA && (wave * 16 + 15) < kf * 32) continue;
            bf16x8 ap = *reinterpret_cast<const bf16x8*>(
                &PsA[(wave * 16 + l16) * LDP + kf * 32 + quad * 8]);
            #pragma unroll
            for (int t = 0; t < 4; ++t) {
                bf16x8 bv = *reinterpret_cast<const bf16x8*>(
                    &Vs[buf][kf][(t * 16 + l16) * 32 + quad * 8]);
                oA[t] = __builtin_amdgcn_mfma_f32_16x16x32_bf16(ap, bv, oA[t], 0, 0, 0);
            }
        }
        if (doB) {
            #pragma unroll
            for (int kf = 0; kf < 2; ++kf) {
                if (diagB && (wave * 16 + 15) < kf * 32) continue;
                bf16x8 ap = *reinterpret_cast<const bf16x8*>(
                    &PsB[(wave * 16 + l16) * LDP + kf * 32 + quad * 8]);
                #pragma unroll
                for (int t = 0; t < 4; ++t) {
                    bf16x8 bv = *reinterpret_cast<const bf16x8*>(
                        &Vs[buf][kf][(t * 16 + l16) * 32 + quad * 8]);
                    oB[t] = __builtin_amdgcn_mfma_f32_16x16x32_bf16(ap, bv, oB[t], 0, 0, 0);
                }
            }
        }

        if (kt + 1 < nkt)
            __syncthreads();             // drains prefetch; guards buffer swap
    }

    #pragma unroll
    for (int off = 1; off < 16; off <<= 1)
        #pragma unroll
        for (int r = 0; r < 4; ++r) {
            lsA[r] += __shfl_xor(lsA[r], off);
            lsB[r] += __shfl_xor(lsB[r], off);
        }

    #pragma unroll
    for (int r = 0; r < 4; ++r) {
        const float invA = 1.0f / lsA[r];
        const float invB = 1.0f / lsB[r];
        const size_t grA = (size_t)(tokBase + qBaseA + wave * 16 + quad * 4 + r) * 1024 + colBase;
        const size_t grB = (size_t)(tokBase + qBaseB + wave * 16 + quad * 4 + r) * 1024 + colBase;
        #pragma unroll
        for (int t = 0; t < 4; ++t) {
            ctx[grA + t * 16 + l16] = f2bf(oA[t][r] * invA);
            ctx[grB + t * 16 + l16] = f2bf(oB[t][r] * invB);
        }
    }
}

// ---------------------------------------------------------------------------
extern "C" void kernel_launch(void* const* d_in, const int* in_sizes, int n_in,
                              void* d_out, int out_size, void* d_ws, size_t ws_size,
                              hipStream_t stream)
{
    const float* x  = (const float*)d_in[0];   // [4096,1024] fp32
    const float* Wq = (const float*)d_in[1];
    const float* Wk = (const float*)d_in[2];
    const float* Wv = (const float*)d_in[3];
    const float* Wo = (const float*)d_in[4];
    const float* bo = (const float*)d_in[5];
    float* out = (float*)d_out;

    // ws (32 MB): xb -> ctx after gemm_qkv; kb -> woT after attn6.
    // d_out doubles as wqkvT scratch until gemm_out64 overwrites it.
    unsigned short* xb     = (unsigned short*)d_ws;           // 8 MB -> ctx
    unsigned short* qb     = xb + (size_t)4096 * 1024;        // 8 MB
    unsigned short* kb     = qb + (size_t)4096 * 1024;        // 8 MB -> woT
    unsigned short* vT     = kb + (size_t)4096 * 1024;        // 8 MB [1024][4096]
    unsigned short* ctx    = xb;
    unsigned short* wqkvT  = (unsigned short*)d_out;          // 6.3 MB scratch
    unsigned short* woT    = kb;

    prep<<<2816, 256, 0, stream>>>(x, xb, Wq, Wk, Wv, wqkvT);

    gemm_qkv<<<dim3(24, 32), 256, 0, stream>>>(xb, wqkvT, qb, kb, vT);

    attn6<<<dim3(16, 32), 256, 0, stream>>>(qb, kb, vT, ctx);

    wconv<<<dim3(16, 16), 256, 0, stream>>>(Wo, woT);

    gemm_out64<<<dim3(8, 64), 256, 0, stream>>>(ctx, woT, out, bo);
}